// Round 7
// baseline (1982.094 us; speedup 1.0000x reference)
//
#include <hip/hip_runtime.h>

// VanillaRNN: BATCH=1024, SEQ=512, HID=512, OUT=10
// h <- tanh(W_hh @ h + W_hx x_t + b_h), 512 steps, then y = W_yh h + b_y.
//
// Round 7: CU-local (zero inter-WG comm), 64 WGs x 256 thr = 4 waves,
// 1 wave/SIMD -> 512 unified regs/lane. R5's "+a" virtual-AGPR pinning was
// correct but over budget at 2 waves/SIMD (192a+128v > 256); R6's hardcoded
// physical AGPRs were corrupted by RA using the same bank within iterations.
// This round: "+a"-pinned VIRTUAL AGPR W at the 512-reg budget:
//   kk 0..10 (K=352): 88 f16x8 frags pinned to AGPRs (352 regs) — intrinsic
//                     MFMA reads srcA straight from AGPR on gfx950.
//   kk 11..14 (K=128): LDS WL (128 KB).
//   kk 15    (K=32):  streamed from L2 each step (laundered ptr, ~32 KB/step,
//                     issued at loop top, latency hidden under phase 1).
// h (16 KB) in LDS in place, 2 barriers/step. All MFMAs are intrinsics
// (compiler owns hazards). Arithmetic identical to R3-R5 (absmax 9.77e-4).
//
// ws: [0,1MB) hG (final h, frag-blocked) | [2MB,2.5MB) W A-frags.

#define BATCH 1024
#define SEQT  512
#define HID   512
#define OUTD  10
#define KA    11   // kk-blocks (of K=32) in AGPRs
#define KL    4    // kk-blocks in LDS (kk 11..14); kk 15 streamed

typedef _Float16 f16;
typedef _Float16 f16x8 __attribute__((ext_vector_type(8)));
typedef _Float16 f16x4 __attribute__((ext_vector_type(4)));
typedef float    f32x4 __attribute__((ext_vector_type(4)));

// W_hh fp32 [H][H] -> fp16 A-fragment layout:
// entry (G*16+kk)*64+lane = f16x8 of A[m][k],
// m = G*16+(lane&15), k = kk*32+((lane>>4)&3)*8+j.  (G = 16-row tile, 0..31)
__global__ void wconv_kernel(const float* __restrict__ Whh, f16* __restrict__ frag) {
    int id = blockIdx.x * blockDim.x + threadIdx.x;   // 0..32767
    int lane = id & 63;
    int kk   = (id >> 6) & 15;
    int G    = id >> 10;
    int m = G * 16 + (lane & 15);
    int k = kk * 32 + ((lane >> 4) & 3) * 8;
    const float* src = Whh + (size_t)m * HID + k;
    f16x8 v;
#pragma unroll
    for (int j = 0; j < 8; ++j) v[j] = (f16)src[j];
    *(f16x8*)(frag + (size_t)id * 8) = v;
}

__device__ __forceinline__ float fast_tanh(float v) {
    v = fminf(fmaxf(v, -15.f), 15.f);
    float e = __expf(2.f * v);
    return (e - 1.f) * __builtin_amdgcn_rcpf(e + 1.f);
}

__global__ __launch_bounds__(256, 1)
__attribute__((amdgpu_waves_per_eu(1, 1)))
void rnn_cu(
    const f16* __restrict__ frag,   // W_hh A-frags (all 16 kk-blocks)
    f16* __restrict__ hG,           // final h, frag-blocked
    const float* __restrict__ x,    // [B][T]
    const float* __restrict__ Whx,  // [H]
    const float* __restrict__ bh)   // [H]
{
    __shared__ f16 HB[8192];        // h, B-frag layout, 16 KB (low ds offsets)
    __shared__ f16 WL[65536];       // W A-frags kk 11..14, 128 KB

    const int tid  = threadIdx.x;
    const int w    = tid >> 6;      // wave: rows [w*128, +128) = G w*8..w*8+7
    const int lane = tid & 63;
    const int n    = lane & 15;
    const int q    = lane >> 4;
    const int bg   = blockIdx.x;    // batch cols [bg*16, +16)

    // ---- h(0) = 0 ----
    {
        f16x8 z;
#pragma unroll
        for (int j = 0; j < 8; ++j) z[j] = (f16)0.f;
        *(f16x8*)&HB[tid * 32]      = z;
        *(f16x8*)&HB[tid * 32 + 8]  = z;
        *(f16x8*)&HB[tid * 32 + 16] = z;
        *(f16x8*)&HB[tid * 32 + 24] = z;
    }

    const f16x8* A = (const f16x8*)frag;

    // ---- stage LDS W (kk 11..14): wave w writes its 32 frags ----
#pragma unroll
    for (int mt = 0; mt < 8; ++mt)
#pragma unroll
        for (int kkl = 0; kkl < KL; ++kkl) {
            int G = w * 8 + mt;
            *(f16x8*)&WL[(size_t)((G * 4 + kkl) * 64 + lane) * 8] =
                A[(size_t)(G * 16 + (KA + kkl)) * 64 + lane];
        }

    // ---- AGPR W (kk 0..10): 88 frags = 352 AGPRs/lane, virtually pinned.
    // "+a" makes each value a non-rematerializable AGPR-class def the
    // allocator must keep live; at 1 wave/SIMD the unified budget (512)
    // fits 352a + ~110v. Intrinsic MFMA reads srcA directly from AGPR.
    f16x8 Wr[KA * 8];
#pragma unroll
    for (int kk = 0; kk < KA; ++kk)
#pragma unroll
        for (int mt = 0; mt < 8; ++mt)
            Wr[kk * 8 + mt] = A[(size_t)((w * 8 + mt) * 16 + kk) * 64 + lane];
#pragma unroll
    for (int i = 0; i < KA * 8; ++i)
        asm volatile("" : "+a"(Wr[i]));

    __syncthreads();

    const int b = bg * 16 + n;
    const float* xp = x + (size_t)b * SEQT;

#pragma unroll 1
    for (int s = 0; s < SEQT; ++s) {
        float xv = xp[s];

        // ---- stream kk 15 (laundered ptr -> stays a per-step L2 load;
        // issued at loop top so latency hides under phase 1) ----
        const f16x8* Ap = A;
        asm volatile("" : "+v"(Ap));
        f16x8 S15[8];
#pragma unroll
        for (int mt = 0; mt < 8; ++mt)
            S15[mt] = Ap[(size_t)((w * 8 + mt) * 16 + 15) * 64 + lane];

        f32x4 acc[8] = {{0,0,0,0},{0,0,0,0},{0,0,0,0},{0,0,0,0},
                        {0,0,0,0},{0,0,0,0},{0,0,0,0},{0,0,0,0}};

        // ---- phase 1: kk 0..10 from AGPRs ----
#pragma unroll
        for (int kk = 0; kk < KA; ++kk) {
            f16x8 bf = *(const f16x8*)&HB[(kk * 64 + lane) * 8];
#pragma unroll
            for (int mt = 0; mt < 8; ++mt)
                acc[mt] = __builtin_amdgcn_mfma_f32_16x16x32_f16(
                    Wr[kk * 8 + mt], bf, acc[mt], 0, 0, 0);
        }

        // ---- phase 2: kk 11..14 from LDS ----
#pragma unroll
        for (int kkl = 0; kkl < KL; ++kkl) {
            f16x8 bf = *(const f16x8*)&HB[((KA + kkl) * 64 + lane) * 8];
#pragma unroll
            for (int mt = 0; mt < 8; ++mt) {
                int G = w * 8 + mt;
                f16x8 a = *(const f16x8*)&WL[(size_t)((G * 4 + kkl) * 64 + lane) * 8];
                acc[mt] = __builtin_amdgcn_mfma_f32_16x16x32_f16(a, bf, acc[mt], 0, 0, 0);
            }
        }

        // ---- phase 3: kk 15 from streamed regs ----
        {
            f16x8 bf15 = *(const f16x8*)&HB[(15 * 64 + lane) * 8];
#pragma unroll
            for (int mt = 0; mt < 8; ++mt)
                acc[mt] = __builtin_amdgcn_mfma_f32_16x16x32_f16(
                    S15[mt], bf15, acc[mt], 0, 0, 0);
        }

        __syncthreads();   // all reads of h(s) done before in-place overwrite

        // Keep Whx/bh loads in-loop (hoisting costs 64 regs -> spill risk).
        const float* wbp = Whx;
        const float* bbp = bh;
        asm volatile("" : "+v"(wbp), "+v"(bbp));

        // ---- epilogue: tanh, write h(s+1) in B-frag layout ----
        // C layout: col n = lane&15, row m = G*16 + q*4 + r.
#pragma unroll
        for (int mt = 0; mt < 8; ++mt) {
            int G  = w * 8 + mt;
            int m0 = G * 16 + q * 4;
            f32x4 whx4 = *(const f32x4*)(wbp + m0);
            f32x4 bh4  = *(const f32x4*)(bbp + m0);
            f16x4 hv;
#pragma unroll
            for (int r = 0; r < 4; ++r) {
                float pre = acc[mt][r] + whx4[r] * xv + bh4[r];
                hv[r] = (f16)fast_tanh(pre);
            }
            int kkd = G >> 1;
            int q2  = (G & 1) * 2 + (q >> 1);
            int j0  = (q & 1) * 4;
            int off = (kkd * 64 + q2 * 16 + n) * 8 + j0;
            if (s < SEQT - 1) {
                *(f16x4*)&HB[off] = hv;
            } else {
                *(f16x4*)(hG + (size_t)(((bg * 16 + kkd) * 64 + q2 * 16 + n) * 8 + j0)) = hv;
            }
        }

        __syncthreads();   // h(s+1) complete before next step's reads
    }
}

// out[b][o] = by[o] + sum_k Wyh[o][k] * h[b][k], h in frag-blocked layout.
__global__ __launch_bounds__(256) void y_kernel(
    const f16* __restrict__ h, const float* __restrict__ Wyh,
    const float* __restrict__ by, float* __restrict__ out)
{
    int id = blockIdx.x * blockDim.x + threadIdx.x;
    if (id >= BATCH * OUTD) return;
    int b = id / OUTD, o = id % OUTD;
    int bg = b >> 4, n = b & 15;
    const float* wrow = Wyh + (size_t)o * HID;
    float s = by[o];
    for (int kk = 0; kk < 16; ++kk)
#pragma unroll
        for (int q2 = 0; q2 < 4; ++q2) {
            f16x8 hv = *(const f16x8*)(h + (size_t)((bg * 16 + kk) * 64 + q2 * 16 + n) * 8);
            const float* wp = wrow + kk * 32 + q2 * 8;
#pragma unroll
            for (int j = 0; j < 8; ++j) s += wp[j] * (float)hv[j];
        }
    out[id] = s;
}

extern "C" void kernel_launch(void* const* d_in, const int* in_sizes, int n_in,
                              void* d_out, int out_size, void* d_ws, size_t ws_size,
                              hipStream_t stream) {
    const float* x   = (const float*)d_in[0];
    const float* Whx = (const float*)d_in[1];
    const float* Whh = (const float*)d_in[2];
    const float* Wyh = (const float*)d_in[3];
    const float* bh  = (const float*)d_in[4];
    const float* by  = (const float*)d_in[5];
    float* out = (float*)d_out;

    char* ws   = (char*)d_ws;
    f16*  hG   = (f16*)ws;                       // 1 MB
    f16*  frag = (f16*)(ws + (2 << 20));         // 512 KB

    wconv_kernel<<<128, 256, 0, stream>>>(Whh, frag);
    rnn_cu<<<64, 256, 0, stream>>>(frag, hG, x, Whx, bh);
    y_kernel<<<(BATCH * OUTD + 255) / 256, 256, 0, stream>>>(hG, Wyh, by, out);
}